// Round 19
// baseline (1075.718 us; speedup 1.0000x reference)
//
#include <hip/hip_runtime.h>
#include <hip/hip_bf16.h>

typedef short s16x8 __attribute__((ext_vector_type(8)));
typedef float f32x4 __attribute__((ext_vector_type(4)));
typedef unsigned short u16x4 __attribute__((ext_vector_type(4)));

#define MFMA16(a, b, c) __builtin_amdgcn_mfma_f32_16x16x32_bf16((a), (b), (c), 0, 0, 0)

__device__ __forceinline__ unsigned short f32_to_bf16(float f) {
  unsigned int u = __builtin_bit_cast(unsigned int, f);
  u += 0x7FFFu + ((u >> 16) & 1u);
  return (unsigned short)(u >> 16);
}

__device__ __forceinline__ void glds16(const unsigned short* g, unsigned short* l) {
  __builtin_amdgcn_global_load_lds(
      (const __attribute__((address_space(1))) void*)g,
      (__attribute__((address_space(3))) void*)l, 16, 0, 0);
}

// ---------- fp32 -> bf16 straight convert (4 elems/thread) ----------
__global__ void cvt_bf16_k(const float* __restrict__ in, unsigned short* __restrict__ out, int n4) {
  int i = blockIdx.x * 256 + threadIdx.x;
  if (i >= n4) return;
  float4 f = ((const float4*)in)[i];
  u16x4 o;
  o.x = f32_to_bf16(f.x); o.y = f32_to_bf16(f.y);
  o.z = f32_to_bf16(f.z); o.w = f32_to_bf16(f.w);
  ((u16x4*)out)[i] = o;
}

// ---------- 4 weights fp32 [D][D] -> bf16 transposed [N][K], one launch ----------
__global__ void cvt_t4_k(const float* __restrict__ Wq, const float* __restrict__ Wk,
                         const float* __restrict__ Wv, const float* __restrict__ Wo,
                         unsigned short* __restrict__ outQKV, unsigned short* __restrict__ outO,
                         int D) {
  int z = blockIdx.z;
  const float* in = (z == 0) ? Wq : (z == 1) ? Wk : (z == 2) ? Wv : Wo;
  unsigned short* out = (z < 3) ? (outQKV + (size_t)z * D * D) : outO;
  __shared__ float tile[32][33];
  int tx = threadIdx.x;
  int nt = D >> 5;
  int bx = blockIdx.x % nt;
  int by = blockIdx.x / nt;
  int r = tx >> 3, c4 = (tx & 7) * 4;
  int k0 = by * 32, n0 = bx * 32;
  float4 f = *(const float4*)(in + (size_t)(k0 + r) * D + n0 + c4);
  tile[r][c4 + 0] = f.x; tile[r][c4 + 1] = f.y;
  tile[r][c4 + 2] = f.z; tile[r][c4 + 3] = f.w;
  __syncthreads();
  u16x4 o;
  o.x = f32_to_bf16(tile[c4 + 0][r]);
  o.y = f32_to_bf16(tile[c4 + 1][r]);
  o.z = f32_to_bf16(tile[c4 + 2][r]);
  o.w = f32_to_bf16(tile[c4 + 3][r]);
  *(u16x4*)(out + (size_t)(n0 + r) * D + k0 + c4) = o;
}

// ---------- QKV GEMM: ring-2 BK=32, 48KB LDS -> 3 blocks/CU ----------
// STAGE-before-compute double buffer (attn2's verified barrier ledger):
// top: STAGE(cur^1, kt+1); vmcnt(3) drains tile kt only; barrier; compute cur;
// bottom barrier seals cur before iter kt+1 overwrites it. Granule-correct
// swizzle s^=((r>>1)&3) (measured 0 conflicts).
template <int OUTF32>
__global__ __launch_bounds__(512, 6) void gemm2b(
    const unsigned short* __restrict__ A, const unsigned short* __restrict__ Bt,
    void* __restrict__ Cv, int M, int N, int K, int ldc) {
  __shared__ unsigned short As[2][256 * 32];
  __shared__ unsigned short Bs[2][128 * 32];
  int t = threadIdx.x, lane = t & 63, w = t >> 6;
  int r16 = lane & 15, kg = lane >> 4;
  int wm = w >> 1, wn = w & 1;
  int nbn = N >> 7;
  int bm = blockIdx.x / nbn, bn = blockIdx.x % nbn;
  const unsigned short* Ag = A + (size_t)bm * 256 * K;
  const unsigned short* Bg = Bt + (size_t)bn * 128 * K;

  const unsigned short* asrc[2];
  int aoff[2];
#pragma unroll
  for (int i = 0; i < 2; ++i) {
    int c = i * 512 + t;
    int row = c >> 2, sl = c & 3;
    asrc[i] = Ag + (size_t)row * K + ((sl ^ ((row >> 1) & 3)) * 8);
    aoff[i] = (i * 512 + (t & ~63)) * 8;
  }
  int brow = t >> 2;
  const unsigned short* bsrc = Bg + (size_t)brow * K + (((t & 3) ^ ((brow >> 1) & 3)) * 8);
  int boff = (t & ~63) * 8;

  auto STAGE = [&](int bi, int kt2) {
    int k0 = kt2 * 32;
    glds16(asrc[0] + k0, &As[bi][aoff[0]]);
    glds16(asrc[1] + k0, &As[bi][aoff[1]]);
    glds16(bsrc + k0, &Bs[bi][boff]);
  };

  f32x4 acc[4][4] = {};
  int nt = K >> 5;
  STAGE(0, 0);
  int cur = 0;
  for (int kt = 0; kt < nt; ++kt) {
    if (kt + 1 < nt) {
      STAGE(cur ^ 1, kt + 1);
      asm volatile("s_waitcnt vmcnt(3)" ::: "memory");
    } else {
      asm volatile("s_waitcnt vmcnt(0)" ::: "memory");
    }
    __builtin_amdgcn_s_barrier();
    __builtin_amdgcn_sched_barrier(0);
    const unsigned short* Al = As[cur];
    const unsigned short* Bl = Bs[cur];
    s16x8 af[4], bfr[4];
#pragma unroll
    for (int mf = 0; mf < 4; ++mf) {
      int row = wm * 64 + mf * 16 + r16;
      af[mf] = *(const s16x8*)&Al[row * 32 + ((kg ^ ((row >> 1) & 3)) * 8)];
    }
#pragma unroll
    for (int nf = 0; nf < 4; ++nf) {
      int row = wn * 64 + nf * 16 + r16;
      bfr[nf] = *(const s16x8*)&Bl[row * 32 + ((kg ^ ((row >> 1) & 3)) * 8)];
    }
    __builtin_amdgcn_s_setprio(1);
#pragma unroll
    for (int mf = 0; mf < 4; ++mf)
#pragma unroll
      for (int nf = 0; nf < 4; ++nf)
        acc[mf][nf] = MFMA16(af[mf], bfr[nf], acc[mf][nf]);
    __builtin_amdgcn_s_setprio(0);
    asm volatile("s_waitcnt lgkmcnt(0)" ::: "memory");
    __builtin_amdgcn_s_barrier();
    __builtin_amdgcn_sched_barrier(0);
    cur ^= 1;
  }
#pragma unroll
  for (int mf = 0; mf < 4; ++mf)
#pragma unroll
    for (int nf = 0; nf < 4; ++nf)
#pragma unroll
      for (int r = 0; r < 4; ++r) {
        int row = bm * 256 + wm * 64 + mf * 16 + kg * 4 + r;
        int col = bn * 128 + wn * 64 + nf * 16 + r16;
        if (OUTF32)
          ((float*)Cv)[(size_t)row * ldc + col] = acc[mf][nf][r];
        else
          ((unsigned short*)Cv)[(size_t)row * ldc + col] = f32_to_bf16(acc[mf][nf][r]);
      }
}

// ---------- GEMM (ring-3 BK=64, measured best for final projection) ----------
template <int OUTF32>
__global__ __launch_bounds__(512, 2) void gemm3(
    const unsigned short* __restrict__ A, const unsigned short* __restrict__ Bt,
    void* __restrict__ Cv, int M, int N, int K, int ldc) {
  __shared__ unsigned short As[3][256 * 64];
  __shared__ unsigned short Bs[3][128 * 64];
  int t = threadIdx.x, lane = t & 63, w = t >> 6;
  int r16 = lane & 15, kg = lane >> 4;
  int wm = w >> 1, wn = w & 1;
  int nbn = N >> 7;
  int bm = blockIdx.x / nbn, bn = blockIdx.x % nbn;
  const unsigned short* Ag = A + (size_t)bm * 256 * K;
  const unsigned short* Bg = Bt + (size_t)bn * 128 * K;

  const unsigned short* asrc[4];
  const unsigned short* bsrc[2];
  int aoff[4], boff[2];
#pragma unroll
  for (int i = 0; i < 4; ++i) {
    int c = i * 512 + t;
    int row = c >> 3, sl = c & 7;
    asrc[i] = Ag + (size_t)row * K + ((sl ^ (row & 7)) * 8);
    aoff[i] = (i * 512 + (t & ~63)) * 8;
  }
#pragma unroll
  for (int i = 0; i < 2; ++i) {
    int c = i * 512 + t;
    int row = c >> 3, sl = c & 7;
    bsrc[i] = Bg + (size_t)row * K + ((sl ^ (row & 7)) * 8);
    boff[i] = (i * 512 + (t & ~63)) * 8;
  }

  auto STAGE = [&](int bi, int kt2) {
    int k0 = kt2 * 64;
#pragma unroll
    for (int i = 0; i < 4; ++i) glds16(asrc[i] + k0, &As[bi][aoff[i]]);
#pragma unroll
    for (int i = 0; i < 2; ++i) glds16(bsrc[i] + k0, &Bs[bi][boff[i]]);
  };

  f32x4 acc[4][4] = {};
  int nt = K >> 6;
  STAGE(0, 0);
  if (nt > 1) STAGE(1, 1);
  int cur = 0;
  for (int kt = 0; kt < nt; ++kt) {
    if (kt + 1 < nt) {
      asm volatile("s_waitcnt vmcnt(6)" ::: "memory");
    } else {
      asm volatile("s_waitcnt vmcnt(0)" ::: "memory");
    }
    __builtin_amdgcn_s_barrier();
    asm volatile("" ::: "memory");
    if (kt + 2 < nt) {
      int s2 = cur + 2; if (s2 >= 3) s2 -= 3;
      STAGE(s2, kt + 2);
    }
    const unsigned short* Al = As[cur];
    s16x8 af[4][2], bfr[4][2];
#pragma unroll
    for (int mf = 0; mf < 4; ++mf) {
      int row = wm * 64 + mf * 16 + r16;
#pragma unroll
      for (int ks = 0; ks < 2; ++ks)
        af[mf][ks] = *(const s16x8*)&Al[row * 64 + (((ks * 4 + kg) ^ (row & 7)) * 8)];
    }
#pragma unroll
    for (int nf = 0; nf < 4; ++nf) {
      int row = wn * 64 + nf * 16 + r16;
#pragma unroll
      for (int ks = 0; ks < 2; ++ks)
        bfr[nf][ks] = *(const s16x8*)&Bs[cur][row * 64 + (((ks * 4 + kg) ^ (row & 7)) * 8)];
    }
    __builtin_amdgcn_s_setprio(1);
#pragma unroll
    for (int ks = 0; ks < 2; ++ks)
#pragma unroll
      for (int mf = 0; mf < 4; ++mf)
#pragma unroll
        for (int nf = 0; nf < 4; ++nf)
          acc[mf][nf] = MFMA16(af[mf][ks], bfr[nf][ks], acc[mf][nf]);
    __builtin_amdgcn_s_setprio(0);
    cur = (cur == 2) ? 0 : cur + 1;
  }
#pragma unroll
  for (int mf = 0; mf < 4; ++mf)
#pragma unroll
    for (int nf = 0; nf < 4; ++nf)
#pragma unroll
      for (int r = 0; r < 4; ++r) {
        int row = bm * 256 + wm * 64 + mf * 16 + kg * 4 + r;
        int col = bn * 128 + wn * 64 + nf * 16 + r16;
        if (OUTF32)
          ((float*)Cv)[(size_t)row * ldc + col] = acc[mf][nf][r];
        else
          ((unsigned short*)Cv)[(size_t)row * ldc + col] = f32_to_bf16(acc[mf][nf][r]);
      }
}

// ---------- V -> chunked V^T layout: chunk(slot=s/8, d) holds V[s=slot*8+j][d] ----------
__global__ __launch_bounds__(256) void vtr_k(const unsigned short* __restrict__ V,
                                             unsigned short* __restrict__ Vt,
                                             int S, int ld) {
  __shared__ unsigned short T[32 * 128];
  int s0 = blockIdx.x * 32, h = blockIdx.y, b = blockIdx.z;
  int H = gridDim.y;
  int t = threadIdx.x;
  const unsigned short* src = V + (size_t)(b * S + s0) * ld + h * 128;
#pragma unroll
  for (int c = 0; c < 2; ++c) {
    int chunk = c * 256 + t;
    int row = chunk >> 4, slot = chunk & 15;
    glds16(src + (size_t)row * ld + slot * 8, &T[(c * 256 + (t & ~63)) * 8]);
  }
  __syncthreads();
  unsigned short* dst = Vt + ((size_t)(b * H + h) * (S >> 3) + (s0 >> 3)) * 1024;
#pragma unroll
  for (int c = 0; c < 2; ++c) {
    int oc = c * 256 + t;
    int sl = oc >> 7, d = oc & 127;
    s16x8 v;
#pragma unroll
    for (int j = 0; j < 8; ++j) v[j] = (short)T[(sl * 8 + j) * 128 + d];
    *(s16x8*)(dst + (size_t)oc * 8) = v;
  }
}

// ---------- causal flash attention (r14 best): 8 waves, QBLK=128, KVBLK=64, dbuf ----------
__global__ __launch_bounds__(512) void attn2_k(
    const unsigned short* __restrict__ Q, const unsigned short* __restrict__ Kx,
    const unsigned short* __restrict__ Vt, unsigned short* __restrict__ O,
    int S, int D, int Bn, int ld) {
  const float scale = 0.08838834764831843f;  // 1/sqrt(128)
  int hb = blockIdx.x;
  int h = hb / Bn, b = hb % Bn;
  int NQ = S >> 7;
  int qt = NQ - 1 - blockIdx.y;  // largest-work blocks first
  int H = D >> 7;
  int t = threadIdx.x, lane = t & 63, w = t >> 6;
  int r16 = lane & 15, kg = lane >> 4;
  const unsigned short* Qb  = Q + (size_t)b * S * ld + h * 128;
  const unsigned short* Kb  = Kx + (size_t)b * S * ld + h * 128;
  const unsigned short* Vtb = Vt + (size_t)(b * H + h) * (S >> 3) * 1024;

  __shared__ unsigned short Kbuf[2][64 * 128];
  __shared__ unsigned short Vbuf[2][64 * 128];
  __shared__ unsigned short Pl[8][16 * 64];

  auto STAGE = [&](int bufi, int kv0) {
    const unsigned short* Ksrc = Kb + (size_t)kv0 * ld;
#pragma unroll
    for (int c = 0; c < 2; ++c) {
      int chunk = c * 512 + t;
      int row = chunk >> 4, slot = chunk & 15;
      glds16(Ksrc + (size_t)row * ld + ((slot ^ (row & 7)) * 8),
             &Kbuf[bufi][(c * 512 + (t & ~63)) * 8]);
    }
    const unsigned short* Vsrc = Vtb + (size_t)(kv0 >> 3) * 1024;
#pragma unroll
    for (int c = 0; c < 2; ++c) {
      int chunk = c * 512 + t;
      glds16(Vsrc + (size_t)chunk * 8, &Vbuf[bufi][(c * 512 + (t & ~63)) * 8]);
    }
  };

  int W0 = qt * 128 + w * 16;
  int qg = W0 + r16;
  s16x8 qf[4];
#pragma unroll
  for (int ks = 0; ks < 4; ++ks)
    qf[ks] = *(const s16x8*)(Qb + (size_t)qg * ld + ks * 32 + kg * 8);
  f32x4 oacc[8] = {};
  float m_st = -1e30f, l_st = 0.f;
  int nt = (qt + 1) * 2;
  int cur = 0;
  STAGE(0, 0);
  __syncthreads();
  for (int it = 0; it < nt; ++it) {
    int kv0 = it * 64;
    if (it + 1 < nt) STAGE(cur ^ 1, (it + 1) * 64);
    const unsigned short* Kl = Kbuf[cur];
    const unsigned short* Vl = Vbuf[cur];
    if (kv0 <= W0 + 15) {
      f32x4 st4[4];
      __builtin_amdgcn_s_setprio(1);
#pragma unroll
      for (int kf = 0; kf < 4; ++kf) {
        f32x4 s = {};
#pragma unroll
        for (int ks = 0; ks < 4; ++ks) {
          int row = kf * 16 + r16;
          s16x8 kfr = *(const s16x8*)&Kl[row * 128 + (((ks * 4 + kg) ^ (row & 7)) * 8)];
          s = MFMA16(kfr, qf[ks], s);  // St[kv][q]
        }
        st4[kf] = s;
      }
      __builtin_amdgcn_s_setprio(0);
      float p[4][4];
      float mx = -1e30f;
#pragma unroll
      for (int kf = 0; kf < 4; ++kf)
#pragma unroll
        for (int r = 0; r < 4; ++r) {
          int kvg = kv0 + kf * 16 + kg * 4 + r;
          float sv = st4[kf][r] * scale;
          sv = (kvg <= qg) ? sv : -1e30f;
          p[kf][r] = sv;
          mx = fmaxf(mx, sv);
        }
      mx = fmaxf(mx, __shfl_xor(mx, 16, 64));
      mx = fmaxf(mx, __shfl_xor(mx, 32, 64));
      // defer-max (T13, THR=0): if no row's max grew, skip rescale entirely
      bool skip = __all(mx <= m_st);
      float m_new = skip ? m_st : fmaxf(m_st, mx);
      float rs = 0.f;
#pragma unroll
      for (int kf = 0; kf < 4; ++kf)
#pragma unroll
        for (int r = 0; r < 4; ++r) {
          float e = __expf(p[kf][r] - m_new);
          p[kf][r] = e;
          rs += e;
        }
      rs += __shfl_xor(rs, 16, 64);
      rs += __shfl_xor(rs, 32, 64);
#pragma unroll
      for (int kf = 0; kf < 4; ++kf) {
        unsigned int lo = (unsigned int)f32_to_bf16(p[kf][0]) | ((unsigned int)f32_to_bf16(p[kf][1]) << 16);
        unsigned int hi = (unsigned int)f32_to_bf16(p[kf][2]) | ((unsigned int)f32_to_bf16(p[kf][3]) << 16);
        int sslot = 2 * kf + (kg >> 1);
        int base = r16 * 64 + ((sslot ^ (r16 & 7)) * 8) + (kg & 1) * 4;
        *(unsigned int*)&Pl[w][base]     = lo;
        *(unsigned int*)&Pl[w][base + 2] = hi;
      }
      asm volatile("s_waitcnt lgkmcnt(0)" ::: "memory");
      __builtin_amdgcn_sched_barrier(0);
      if (!skip) {
        float alpha = __expf(m_st - m_new);
        l_st = l_st * alpha + rs;
        m_st = m_new;
        float ar[4];
#pragma unroll
        for (int r = 0; r < 4; ++r) ar[r] = __shfl(alpha, kg * 4 + r, 64);
#pragma unroll
        for (int f = 0; f < 8; ++f)
#pragma unroll
          for (int r = 0; r < 4; ++r) oacc[f][r] *= ar[r];
      } else {
        l_st += rs;
      }
      __builtin_amdgcn_s_setprio(1);
#pragma unroll
      for (int tt = 0; tt < 2; ++tt) {
        s16x8 pf = *(const s16x8*)&Pl[w][r16 * 64 + (((4 * tt + kg) ^ (r16 & 7)) * 8)];
#pragma unroll
        for (int f = 0; f < 8; ++f) {
          s16x8 vf = *(const s16x8*)&Vl[((4 * tt + kg) * 128 + f * 16 + r16) * 8];
          oacc[f] = MFMA16(pf, vf, oacc[f]);  // O[q][d]
        }
      }
      __builtin_amdgcn_s_setprio(0);
    }
    __syncthreads();
    cur ^= 1;
  }
  float linv = 1.0f / l_st;
  float lr[4];
#pragma unroll
  for (int r = 0; r < 4; ++r) lr[r] = __shfl(linv, kg * 4 + r, 64);
#pragma unroll
  for (int f = 0; f < 8; ++f)
#pragma unroll
    for (int r = 0; r < 4; ++r) {
      size_t idx = ((size_t)b * S + W0 + kg * 4 + r) * D + h * 128 + f * 16 + r16;
      O[idx] = f32_to_bf16(oacc[f][r] * lr[r]);
    }
}

extern "C" void kernel_launch(void* const* d_in, const int* in_sizes, int n_in,
                              void* d_out, int out_size, void* d_ws, size_t ws_size,
                              hipStream_t stream) {
  const float* x  = (const float*)d_in[0];
  const float* Wq = (const float*)d_in[1];
  const float* Wk = (const float*)d_in[2];
  const float* Wv = (const float*)d_in[3];
  const float* Wo = (const float*)d_in[4];
  const int D = 2048, H = 16;
  const int M = in_sizes[0] / D;  // B*S = 4096
  const int B = 2, S = M / B;     // 2048
  const int LD = 3 * D;           // 6144, fused QKV row stride

  unsigned short* xb    = (unsigned short*)d_ws;         // M*D
  unsigned short* Wqkvt = xb + (size_t)M * D;            // 3*D*D
  unsigned short* Wot   = Wqkvt + (size_t)3 * D * D;     // D*D
  unsigned short* QKVb  = Wot + (size_t)D * D;           // M*3D
  unsigned short* Ob    = xb;     // reuse xb after QKV GEMM
  unsigned short* VtA   = Wqkvt;  // reuse Wqkvt after QKV GEMM

  int n4 = M * D / 4;
  cvt_bf16_k<<<(n4 + 255) / 256, 256, 0, stream>>>(x, xb, n4);
  int tgrid = (D / 32) * (D / 32);
  cvt_t4_k<<<dim3(tgrid, 1, 4), 256, 0, stream>>>(Wq, Wk, Wv, Wo, Wqkvt, Wot, D);

  // Fused QKV projection: [M,2048] @ [6144,2048]^T -> [M,6144]
  gemm2b<0><<<(M / 256) * (LD / 128), 512, 0, stream>>>(xb, Wqkvt, QKVb, M, LD, D, LD);

  vtr_k<<<dim3(S / 32, H, B), 256, 0, stream>>>(QKVb + 2 * D, VtA, S, LD);

  attn2_k<<<dim3(H * B, S / 128), 512, 0, stream>>>(QKVb, QKVb + D, VtA, Ob, S, D, B, LD);

  gemm3<1><<<(M / 256) * (D / 128), 512, 0, stream>>>(Ob, Wot, d_out, M, D, D, D);
}

// Round 20
// 274.326 us; speedup vs baseline: 3.9213x; 3.9213x over previous
//
#include <hip/hip_runtime.h>
#include <hip/hip_bf16.h>

typedef short s16x8 __attribute__((ext_vector_type(8)));
typedef float f32x4 __attribute__((ext_vector_type(4)));
typedef unsigned short u16x4 __attribute__((ext_vector_type(4)));

#define MFMA16(a, b, c) __builtin_amdgcn_mfma_f32_16x16x32_bf16((a), (b), (c), 0, 0, 0)

__device__ __forceinline__ unsigned short f32_to_bf16(float f) {
  unsigned int u = __builtin_bit_cast(unsigned int, f);
  u += 0x7FFFu + ((u >> 16) & 1u);
  return (unsigned short)(u >> 16);
}

__device__ __forceinline__ void glds16(const unsigned short* g, unsigned short* l) {
  __builtin_amdgcn_global_load_lds(
      (const __attribute__((address_space(1))) void*)g,
      (__attribute__((address_space(3))) void*)l, 16, 0, 0);
}

// ---------- fp32 -> bf16 straight convert (4 elems/thread) ----------
__global__ void cvt_bf16_k(const float* __restrict__ in, unsigned short* __restrict__ out, int n4) {
  int i = blockIdx.x * 256 + threadIdx.x;
  if (i >= n4) return;
  float4 f = ((const float4*)in)[i];
  u16x4 o;
  o.x = f32_to_bf16(f.x); o.y = f32_to_bf16(f.y);
  o.z = f32_to_bf16(f.z); o.w = f32_to_bf16(f.w);
  ((u16x4*)out)[i] = o;
}

// ---------- 4 weights fp32 [D][D] -> bf16 transposed [N][K], one launch ----------
__global__ void cvt_t4_k(const float* __restrict__ Wq, const float* __restrict__ Wk,
                         const float* __restrict__ Wv, const float* __restrict__ Wo,
                         unsigned short* __restrict__ outQKV, unsigned short* __restrict__ outO,
                         int D) {
  int z = blockIdx.z;
  const float* in = (z == 0) ? Wq : (z == 1) ? Wk : (z == 2) ? Wv : Wo;
  unsigned short* out = (z < 3) ? (outQKV + (size_t)z * D * D) : outO;
  __shared__ float tile[32][33];
  int tx = threadIdx.x;
  int nt = D >> 5;
  int bx = blockIdx.x % nt;
  int by = blockIdx.x / nt;
  int r = tx >> 3, c4 = (tx & 7) * 4;
  int k0 = by * 32, n0 = bx * 32;
  float4 f = *(const float4*)(in + (size_t)(k0 + r) * D + n0 + c4);
  tile[r][c4 + 0] = f.x; tile[r][c4 + 1] = f.y;
  tile[r][c4 + 2] = f.z; tile[r][c4 + 3] = f.w;
  __syncthreads();
  u16x4 o;
  o.x = f32_to_bf16(tile[c4 + 0][r]);
  o.y = f32_to_bf16(tile[c4 + 1][r]);
  o.z = f32_to_bf16(tile[c4 + 2][r]);
  o.w = f32_to_bf16(tile[c4 + 3][r]);
  *(u16x4*)(out + (size_t)(n0 + r) * D + k0 + c4) = o;
}

// ---------- QKV GEMM: ring-2 BK=32, 48KB LDS -> 3 blocks/CU (LDS-limited) ----------
// launch_bounds(512,4): same regalloc budget as proven gemm3b (56 VGPR, no
// spill); LDS 48KB gives 3 blocks/CU. STAGE-before-compute double buffer:
// top STAGE(cur^1); vmcnt(3) drains tile kt; barrier; compute; lgkm drain +
// barrier seals cur before next overwrite. Granule-correct swizzle (0 conflicts).
template <int OUTF32>
__global__ __launch_bounds__(512, 4) void gemm2b(
    const unsigned short* __restrict__ A, const unsigned short* __restrict__ Bt,
    void* __restrict__ Cv, int M, int N, int K, int ldc) {
  __shared__ unsigned short As[2][256 * 32];
  __shared__ unsigned short Bs[2][128 * 32];
  int t = threadIdx.x, lane = t & 63, w = t >> 6;
  int r16 = lane & 15, kg = lane >> 4;
  int wm = w >> 1, wn = w & 1;
  int nbn = N >> 7;
  int bm = blockIdx.x / nbn, bn = blockIdx.x % nbn;
  const unsigned short* Ag = A + (size_t)bm * 256 * K;
  const unsigned short* Bg = Bt + (size_t)bn * 128 * K;

  const unsigned short* asrc[2];
  int aoff[2];
#pragma unroll
  for (int i = 0; i < 2; ++i) {
    int c = i * 512 + t;
    int row = c >> 2, sl = c & 3;
    asrc[i] = Ag + (size_t)row * K + ((sl ^ ((row >> 1) & 3)) * 8);
    aoff[i] = (i * 512 + (t & ~63)) * 8;
  }
  int brow = t >> 2;
  const unsigned short* bsrc = Bg + (size_t)brow * K + (((t & 3) ^ ((brow >> 1) & 3)) * 8);
  int boff = (t & ~63) * 8;

  auto STAGE = [&](int bi, int kt2) {
    int k0 = kt2 * 32;
    glds16(asrc[0] + k0, &As[bi][aoff[0]]);
    glds16(asrc[1] + k0, &As[bi][aoff[1]]);
    glds16(bsrc + k0, &Bs[bi][boff]);
  };

  f32x4 acc[4][4] = {};
  int nt = K >> 5;
  STAGE(0, 0);
  int cur = 0;
  for (int kt = 0; kt < nt; ++kt) {
    if (kt + 1 < nt) {
      STAGE(cur ^ 1, kt + 1);
      asm volatile("s_waitcnt vmcnt(3)" ::: "memory");
    } else {
      asm volatile("s_waitcnt vmcnt(0)" ::: "memory");
    }
    __builtin_amdgcn_s_barrier();
    __builtin_amdgcn_sched_barrier(0);
    const unsigned short* Al = As[cur];
    const unsigned short* Bl = Bs[cur];
    s16x8 af[4], bfr[4];
#pragma unroll
    for (int mf = 0; mf < 4; ++mf) {
      int row = wm * 64 + mf * 16 + r16;
      af[mf] = *(const s16x8*)&Al[row * 32 + ((kg ^ ((row >> 1) & 3)) * 8)];
    }
#pragma unroll
    for (int nf = 0; nf < 4; ++nf) {
      int row = wn * 64 + nf * 16 + r16;
      bfr[nf] = *(const s16x8*)&Bl[row * 32 + ((kg ^ ((row >> 1) & 3)) * 8)];
    }
    __builtin_amdgcn_s_setprio(1);
#pragma unroll
    for (int mf = 0; mf < 4; ++mf)
#pragma unroll
      for (int nf = 0; nf < 4; ++nf)
        acc[mf][nf] = MFMA16(af[mf], bfr[nf], acc[mf][nf]);
    __builtin_amdgcn_s_setprio(0);
    asm volatile("s_waitcnt lgkmcnt(0)" ::: "memory");
    __builtin_amdgcn_s_barrier();
    __builtin_amdgcn_sched_barrier(0);
    cur ^= 1;
  }
#pragma unroll
  for (int mf = 0; mf < 4; ++mf)
#pragma unroll
    for (int nf = 0; nf < 4; ++nf)
#pragma unroll
      for (int r = 0; r < 4; ++r) {
        int row = bm * 256 + wm * 64 + mf * 16 + kg * 4 + r;
        int col = bn * 128 + wn * 64 + nf * 16 + r16;
        if (OUTF32)
          ((float*)Cv)[(size_t)row * ldc + col] = acc[mf][nf][r];
        else
          ((unsigned short*)Cv)[(size_t)row * ldc + col] = f32_to_bf16(acc[mf][nf][r]);
      }
}

// ---------- GEMM (ring-3 BK=64, measured best for final projection) ----------
template <int OUTF32>
__global__ __launch_bounds__(512, 2) void gemm3(
    const unsigned short* __restrict__ A, const unsigned short* __restrict__ Bt,
    void* __restrict__ Cv, int M, int N, int K, int ldc) {
  __shared__ unsigned short As[3][256 * 64];
  __shared__ unsigned short Bs[3][128 * 64];
  int t = threadIdx.x, lane = t & 63, w = t >> 6;
  int r16 = lane & 15, kg = lane >> 4;
  int wm = w >> 1, wn = w & 1;
  int nbn = N >> 7;
  int bm = blockIdx.x / nbn, bn = blockIdx.x % nbn;
  const unsigned short* Ag = A + (size_t)bm * 256 * K;
  const unsigned short* Bg = Bt + (size_t)bn * 128 * K;

  const unsigned short* asrc[4];
  const unsigned short* bsrc[2];
  int aoff[4], boff[2];
#pragma unroll
  for (int i = 0; i < 4; ++i) {
    int c = i * 512 + t;
    int row = c >> 3, sl = c & 7;
    asrc[i] = Ag + (size_t)row * K + ((sl ^ (row & 7)) * 8);
    aoff[i] = (i * 512 + (t & ~63)) * 8;
  }
#pragma unroll
  for (int i = 0; i < 2; ++i) {
    int c = i * 512 + t;
    int row = c >> 3, sl = c & 7;
    bsrc[i] = Bg + (size_t)row * K + ((sl ^ (row & 7)) * 8);
    boff[i] = (i * 512 + (t & ~63)) * 8;
  }

  auto STAGE = [&](int bi, int kt2) {
    int k0 = kt2 * 64;
#pragma unroll
    for (int i = 0; i < 4; ++i) glds16(asrc[i] + k0, &As[bi][aoff[i]]);
#pragma unroll
    for (int i = 0; i < 2; ++i) glds16(bsrc[i] + k0, &Bs[bi][boff[i]]);
  };

  f32x4 acc[4][4] = {};
  int nt = K >> 6;
  STAGE(0, 0);
  if (nt > 1) STAGE(1, 1);
  int cur = 0;
  for (int kt = 0; kt < nt; ++kt) {
    if (kt + 1 < nt) {
      asm volatile("s_waitcnt vmcnt(6)" ::: "memory");
    } else {
      asm volatile("s_waitcnt vmcnt(0)" ::: "memory");
    }
    __builtin_amdgcn_s_barrier();
    asm volatile("" ::: "memory");
    if (kt + 2 < nt) {
      int s2 = cur + 2; if (s2 >= 3) s2 -= 3;
      STAGE(s2, kt + 2);
    }
    const unsigned short* Al = As[cur];
    s16x8 af[4][2], bfr[4][2];
#pragma unroll
    for (int mf = 0; mf < 4; ++mf) {
      int row = wm * 64 + mf * 16 + r16;
#pragma unroll
      for (int ks = 0; ks < 2; ++ks)
        af[mf][ks] = *(const s16x8*)&Al[row * 64 + (((ks * 4 + kg) ^ (row & 7)) * 8)];
    }
#pragma unroll
    for (int nf = 0; nf < 4; ++nf) {
      int row = wn * 64 + nf * 16 + r16;
#pragma unroll
      for (int ks = 0; ks < 2; ++ks)
        bfr[nf][ks] = *(const s16x8*)&Bs[cur][row * 64 + (((ks * 4 + kg) ^ (row & 7)) * 8)];
    }
    __builtin_amdgcn_s_setprio(1);
#pragma unroll
    for (int ks = 0; ks < 2; ++ks)
#pragma unroll
      for (int mf = 0; mf < 4; ++mf)
#pragma unroll
        for (int nf = 0; nf < 4; ++nf)
          acc[mf][nf] = MFMA16(af[mf][ks], bfr[nf][ks], acc[mf][nf]);
    __builtin_amdgcn_s_setprio(0);
    cur = (cur == 2) ? 0 : cur + 1;
  }
#pragma unroll
  for (int mf = 0; mf < 4; ++mf)
#pragma unroll
    for (int nf = 0; nf < 4; ++nf)
#pragma unroll
      for (int r = 0; r < 4; ++r) {
        int row = bm * 256 + wm * 64 + mf * 16 + kg * 4 + r;
        int col = bn * 128 + wn * 64 + nf * 16 + r16;
        if (OUTF32)
          ((float*)Cv)[(size_t)row * ldc + col] = acc[mf][nf][r];
        else
          ((unsigned short*)Cv)[(size_t)row * ldc + col] = f32_to_bf16(acc[mf][nf][r]);
      }
}

// ---------- V -> chunked V^T layout: chunk(slot=s/8, d) holds V[s=slot*8+j][d] ----------
__global__ __launch_bounds__(256) void vtr_k(const unsigned short* __restrict__ V,
                                             unsigned short* __restrict__ Vt,
                                             int S, int ld) {
  __shared__ unsigned short T[32 * 128];
  int s0 = blockIdx.x * 32, h = blockIdx.y, b = blockIdx.z;
  int H = gridDim.y;
  int t = threadIdx.x;
  const unsigned short* src = V + (size_t)(b * S + s0) * ld + h * 128;
#pragma unroll
  for (int c = 0; c < 2; ++c) {
    int chunk = c * 256 + t;
    int row = chunk >> 4, slot = chunk & 15;
    glds16(src + (size_t)row * ld + slot * 8, &T[(c * 256 + (t & ~63)) * 8]);
  }
  __syncthreads();
  unsigned short* dst = Vt + ((size_t)(b * H + h) * (S >> 3) + (s0 >> 3)) * 1024;
#pragma unroll
  for (int c = 0; c < 2; ++c) {
    int oc = c * 256 + t;
    int sl = oc >> 7, d = oc & 127;
    s16x8 v;
#pragma unroll
    for (int j = 0; j < 8; ++j) v[j] = (short)T[(sl * 8 + j) * 128 + d];
    *(s16x8*)(dst + (size_t)oc * 8) = v;
  }
}

// ---------- causal flash attention (r14 best): 8 waves, QBLK=128, KVBLK=64, dbuf ----------
__global__ __launch_bounds__(512) void attn2_k(
    const unsigned short* __restrict__ Q, const unsigned short* __restrict__ Kx,
    const unsigned short* __restrict__ Vt, unsigned short* __restrict__ O,
    int S, int D, int Bn, int ld) {
  const float scale = 0.08838834764831843f;  // 1/sqrt(128)
  int hb = blockIdx.x;
  int h = hb / Bn, b = hb % Bn;
  int NQ = S >> 7;
  int qt = NQ - 1 - blockIdx.y;  // largest-work blocks first
  int H = D >> 7;
  int t = threadIdx.x, lane = t & 63, w = t >> 6;
  int r16 = lane & 15, kg = lane >> 4;
  const unsigned short* Qb  = Q + (size_t)b * S * ld + h * 128;
  const unsigned short* Kb  = Kx + (size_t)b * S * ld + h * 128;
  const unsigned short* Vtb = Vt + (size_t)(b * H + h) * (S >> 3) * 1024;

  __shared__ unsigned short Kbuf[2][64 * 128];
  __shared__ unsigned short Vbuf[2][64 * 128];
  __shared__ unsigned short Pl[8][16 * 64];

  auto STAGE = [&](int bufi, int kv0) {
    const unsigned short* Ksrc = Kb + (size_t)kv0 * ld;
#pragma unroll
    for (int c = 0; c < 2; ++c) {
      int chunk = c * 512 + t;
      int row = chunk >> 4, slot = chunk & 15;
      glds16(Ksrc + (size_t)row * ld + ((slot ^ (row & 7)) * 8),
             &Kbuf[bufi][(c * 512 + (t & ~63)) * 8]);
    }
    const unsigned short* Vsrc = Vtb + (size_t)(kv0 >> 3) * 1024;
#pragma unroll
    for (int c = 0; c < 2; ++c) {
      int chunk = c * 512 + t;
      glds16(Vsrc + (size_t)chunk * 8, &Vbuf[bufi][(c * 512 + (t & ~63)) * 8]);
    }
  };

  int W0 = qt * 128 + w * 16;
  int qg = W0 + r16;
  s16x8 qf[4];
#pragma unroll
  for (int ks = 0; ks < 4; ++ks)
    qf[ks] = *(const s16x8*)(Qb + (size_t)qg * ld + ks * 32 + kg * 8);
  f32x4 oacc[8] = {};
  float m_st = -1e30f, l_st = 0.f;
  int nt = (qt + 1) * 2;
  int cur = 0;
  STAGE(0, 0);
  __syncthreads();
  for (int it = 0; it < nt; ++it) {
    int kv0 = it * 64;
    if (it + 1 < nt) STAGE(cur ^ 1, (it + 1) * 64);
    const unsigned short* Kl = Kbuf[cur];
    const unsigned short* Vl = Vbuf[cur];
    if (kv0 <= W0 + 15) {
      f32x4 st4[4];
      __builtin_amdgcn_s_setprio(1);
#pragma unroll
      for (int kf = 0; kf < 4; ++kf) {
        f32x4 s = {};
#pragma unroll
        for (int ks = 0; ks < 4; ++ks) {
          int row = kf * 16 + r16;
          s16x8 kfr = *(const s16x8*)&Kl[row * 128 + (((ks * 4 + kg) ^ (row & 7)) * 8)];
          s = MFMA16(kfr, qf[ks], s);  // St[kv][q]
        }
        st4[kf] = s;
      }
      __builtin_amdgcn_s_setprio(0);
      float p[4][4];
      float mx = -1e30f;
#pragma unroll
      for (int kf = 0; kf < 4; ++kf)
#pragma unroll
        for (int r = 0; r < 4; ++r) {
          int kvg = kv0 + kf * 16 + kg * 4 + r;
          float sv = st4[kf][r] * scale;
          sv = (kvg <= qg) ? sv : -1e30f;
          p[kf][r] = sv;
          mx = fmaxf(mx, sv);
        }
      mx = fmaxf(mx, __shfl_xor(mx, 16, 64));
      mx = fmaxf(mx, __shfl_xor(mx, 32, 64));
      // defer-max (T13, THR=0): if no row's max grew, skip rescale entirely
      bool skip = __all(mx <= m_st);
      float m_new = skip ? m_st : fmaxf(m_st, mx);
      float rs = 0.f;
#pragma unroll
      for (int kf = 0; kf < 4; ++kf)
#pragma unroll
        for (int r = 0; r < 4; ++r) {
          float e = __expf(p[kf][r] - m_new);
          p[kf][r] = e;
          rs += e;
        }
      rs += __shfl_xor(rs, 16, 64);
      rs += __shfl_xor(rs, 32, 64);
#pragma unroll
      for (int kf = 0; kf < 4; ++kf) {
        unsigned int lo = (unsigned int)f32_to_bf16(p[kf][0]) | ((unsigned int)f32_to_bf16(p[kf][1]) << 16);
        unsigned int hi = (unsigned int)f32_to_bf16(p[kf][2]) | ((unsigned int)f32_to_bf16(p[kf][3]) << 16);
        int sslot = 2 * kf + (kg >> 1);
        int base = r16 * 64 + ((sslot ^ (r16 & 7)) * 8) + (kg & 1) * 4;
        *(unsigned int*)&Pl[w][base]     = lo;
        *(unsigned int*)&Pl[w][base + 2] = hi;
      }
      asm volatile("s_waitcnt lgkmcnt(0)" ::: "memory");
      __builtin_amdgcn_sched_barrier(0);
      if (!skip) {
        float alpha = __expf(m_st - m_new);
        l_st = l_st * alpha + rs;
        m_st = m_new;
        float ar[4];
#pragma unroll
        for (int r = 0; r < 4; ++r) ar[r] = __shfl(alpha, kg * 4 + r, 64);
#pragma unroll
        for (int f = 0; f < 8; ++f)
#pragma unroll
          for (int r = 0; r < 4; ++r) oacc[f][r] *= ar[r];
      } else {
        l_st += rs;
      }
      __builtin_amdgcn_s_setprio(1);
#pragma unroll
      for (int tt = 0; tt < 2; ++tt) {
        s16x8 pf = *(const s16x8*)&Pl[w][r16 * 64 + (((4 * tt + kg) ^ (r16 & 7)) * 8)];
#pragma unroll
        for (int f = 0; f < 8; ++f) {
          s16x8 vf = *(const s16x8*)&Vl[((4 * tt + kg) * 128 + f * 16 + r16) * 8];
          oacc[f] = MFMA16(pf, vf, oacc[f]);  // O[q][d]
        }
      }
      __builtin_amdgcn_s_setprio(0);
    }
    __syncthreads();
    cur ^= 1;
  }
  float linv = 1.0f / l_st;
  float lr[4];
#pragma unroll
  for (int r = 0; r < 4; ++r) lr[r] = __shfl(linv, kg * 4 + r, 64);
#pragma unroll
  for (int f = 0; f < 8; ++f)
#pragma unroll
    for (int r = 0; r < 4; ++r) {
      size_t idx = ((size_t)b * S + W0 + kg * 4 + r) * D + h * 128 + f * 16 + r16;
      O[idx] = f32_to_bf16(oacc[f][r] * lr[r]);
    }
}

extern "C" void kernel_launch(void* const* d_in, const int* in_sizes, int n_in,
                              void* d_out, int out_size, void* d_ws, size_t ws_size,
                              hipStream_t stream) {
  const float* x  = (const float*)d_in[0];
  const float* Wq = (const float*)d_in[1];
  const float* Wk = (const float*)d_in[2];
  const float* Wv = (const float*)d_in[3];
  const float* Wo = (const float*)d_in[4];
  const int D = 2048, H = 16;
  const int M = in_sizes[0] / D;  // B*S = 4096
  const int B = 2, S = M / B;     // 2048
  const int LD = 3 * D;           // 6144, fused QKV row stride

  unsigned short* xb    = (unsigned short*)d_ws;         // M*D
  unsigned short* Wqkvt = xb + (size_t)M * D;            // 3*D*D
  unsigned short* Wot   = Wqkvt + (size_t)3 * D * D;     // D*D
  unsigned short* QKVb  = Wot + (size_t)D * D;           // M*3D
  unsigned short* Ob    = xb;     // reuse xb after QKV GEMM
  unsigned short* VtA   = Wqkvt;  // reuse Wqkvt after QKV GEMM

  int n4 = M * D / 4;
  cvt_bf16_k<<<(n4 + 255) / 256, 256, 0, stream>>>(x, xb, n4);
  int tgrid = (D / 32) * (D / 32);
  cvt_t4_k<<<dim3(tgrid, 1, 4), 256, 0, stream>>>(Wq, Wk, Wv, Wo, Wqkvt, Wot, D);

  // Fused QKV projection: [M,2048] @ [6144,2048]^T -> [M,6144]
  gemm2b<0><<<(M / 256) * (LD / 128), 512, 0, stream>>>(xb, Wqkvt, QKVb, M, LD, D, LD);

  vtr_k<<<dim3(S / 32, H, B), 256, 0, stream>>>(QKVb + 2 * D, VtA, S, LD);

  attn2_k<<<dim3(H * B, S / 128), 512, 0, stream>>>(QKVb, QKVb + D, VtA, Ob, S, D, B, LD);

  gemm3<1><<<(M / 256) * (D / 128), 512, 0, stream>>>(Ob, Wot, d_out, M, D, D, D);
}